// Round 1
// baseline (1337.279 us; speedup 1.0000x reference)
//
#include <hip/hip_runtime.h>

#define NE 800000
#define NN 50000
#define HD 128
#define FFD 512

typedef __bf16 bf16;
typedef bf16 bf16x8 __attribute__((ext_vector_type(8)));
typedef float f32x4 __attribute__((ext_vector_type(4)));

__device__ __forceinline__ float gelu_f(float x) {
    return 0.5f * x * (1.0f + erff(x * 0.70710678118654752f));
}

__device__ __forceinline__ bf16x8 cvt8(f32x4 a, f32x4 b) {
    bf16x8 t;
    t[0] = (bf16)a[0]; t[1] = (bf16)a[1]; t[2] = (bf16)a[2]; t[3] = (bf16)a[3];
    t[4] = (bf16)b[0]; t[5] = (bf16)b[1]; t[6] = (bf16)b[2]; t[7] = (bf16)b[3];
    return t;
}

// ---- weight fp32 -> bf16 pre-convert (once per call, into ws) ----
// layout (bf16 elems): W1 @0 (49152), W2 @49152 (16384), W3 @65536 (16384),
//                      W_in @81920 (65536), W_out @147456 (65536). total 212992.
__global__ void cvt_weights(const float* __restrict__ W1, const float* __restrict__ W2,
                            const float* __restrict__ W3, const float* __restrict__ Win,
                            const float* __restrict__ Wout, bf16* __restrict__ o) {
    int i = blockIdx.x * 256 + threadIdx.x;
    if (i < 49152)        o[i] = (bf16)W1[i];
    else if (i < 65536)   o[i] = (bf16)W2[i - 49152];
    else if (i < 81920)   o[i] = (bf16)W3[i - 65536];
    else if (i < 147456)  o[i] = (bf16)Win[i - 81920];
    else if (i < 212992)  o[i] = (bf16)Wout[i - 147456];
}

__global__ void hist_kernel(const int* __restrict__ src, int* __restrict__ cnt) {
    int i = blockIdx.x * 256 + threadIdx.x;
    if (i < NE) atomicAdd(cnt + src[i], 1);
}

// ---- edge MLP: gather-concat -> gelu(W1) -> gelu(W2) -> W3 -> atomic scatter ----
// block = 256 thr (4 waves, 2x2 wave grid), tile = 128 edges x 128 cols.
__global__ __launch_bounds__(256, 2) void edge_mlp(
    const float* __restrict__ hV, const float* __restrict__ hE,
    const int* __restrict__ src, const int* __restrict__ dst,
    const bf16* __restrict__ W1b, const bf16* __restrict__ W2b, const bf16* __restrict__ W3b,
    const float* __restrict__ b1, const float* __restrict__ b2, const float* __restrict__ b3,
    float* __restrict__ segsum)
{
    __shared__ bf16 lx[128][136];   // +8 pad: row stride 272B -> 2-way (free) LDS access
    const int tid  = threadIdx.x;
    const int wave = tid >> 6, lane = tid & 63;
    const int wr = wave >> 1, wc = wave & 1;
    const int quad = lane >> 4, l16 = lane & 15;
    const int row0 = blockIdx.x * 128;

    int arow[4], asrc[4], adst[4];
#pragma unroll
    for (int rt = 0; rt < 4; ++rt) {
        int r = row0 + wr * 64 + rt * 16 + l16;
        arow[rt] = r; asrc[rt] = src[r]; adst[rt] = dst[r];
    }

    f32x4 acc[4][4];
#pragma unroll
    for (int i = 0; i < 4; ++i)
#pragma unroll
        for (int j = 0; j < 4; ++j) acc[i][j] = (f32x4){0.f, 0.f, 0.f, 0.f};

    // ---- layer 1: K = 384 = [hV[src] | hE | hV[dst]] ----
#pragma unroll
    for (int ks = 0; ks < 12; ++ks) {
        const int k = ks * 32 + quad * 8;
        bf16x8 a[4];
#pragma unroll
        for (int rt = 0; rt < 4; ++rt) {
            const float* p;
            if (ks < 4)      p = hV + (size_t)asrc[rt] * HD + k;
            else if (ks < 8) p = hE + (size_t)arow[rt] * HD + (k - 128);
            else             p = hV + (size_t)adst[rt] * HD + (k - 256);
            f32x4 f0 = *(const f32x4*)p;
            f32x4 f1 = *(const f32x4*)(p + 4);
            a[rt] = cvt8(f0, f1);
        }
        bf16x8 b[4];
#pragma unroll
        for (int ct = 0; ct < 4; ++ct) {
            int col = wc * 64 + ct * 16 + l16;
            b[ct] = *(const bf16x8*)(W1b + (size_t)col * 384 + ks * 32 + quad * 8);
        }
#pragma unroll
        for (int rt = 0; rt < 4; ++rt)
#pragma unroll
            for (int ct = 0; ct < 4; ++ct)
                acc[rt][ct] = __builtin_amdgcn_mfma_f32_16x16x32_bf16(a[rt], b[ct], acc[rt][ct], 0, 0, 0);
    }

    // epilogue 1 -> lx (gelu, bf16). C/D layout: col=lane&15, row=quad*4+reg.
#pragma unroll
    for (int ct = 0; ct < 4; ++ct) {
        int col = wc * 64 + ct * 16 + l16;
        float bias = b1[col];
#pragma unroll
        for (int rt = 0; rt < 4; ++rt)
#pragma unroll
            for (int r = 0; r < 4; ++r)
                lx[wr * 64 + rt * 16 + quad * 4 + r][col] = (bf16)gelu_f(acc[rt][ct][r] + bias);
    }
    __syncthreads();

    // ---- layer 2: K = 128 ----
#pragma unroll
    for (int i = 0; i < 4; ++i)
#pragma unroll
        for (int j = 0; j < 4; ++j) acc[i][j] = (f32x4){0.f, 0.f, 0.f, 0.f};
#pragma unroll
    for (int ks = 0; ks < 4; ++ks) {
        bf16x8 a[4], b[4];
#pragma unroll
        for (int rt = 0; rt < 4; ++rt)
            a[rt] = *(const bf16x8*)&lx[wr * 64 + rt * 16 + l16][ks * 32 + quad * 8];
#pragma unroll
        for (int ct = 0; ct < 4; ++ct)
            b[ct] = *(const bf16x8*)(W2b + (size_t)(wc * 64 + ct * 16 + l16) * HD + ks * 32 + quad * 8);
#pragma unroll
        for (int rt = 0; rt < 4; ++rt)
#pragma unroll
            for (int ct = 0; ct < 4; ++ct)
                acc[rt][ct] = __builtin_amdgcn_mfma_f32_16x16x32_bf16(a[rt], b[ct], acc[rt][ct], 0, 0, 0);
    }
    __syncthreads();   // all waves done reading lx before overwrite

    // epilogue 2 -> lx (gelu, bf16)
#pragma unroll
    for (int ct = 0; ct < 4; ++ct) {
        int col = wc * 64 + ct * 16 + l16;
        float bias = b2[col];
#pragma unroll
        for (int rt = 0; rt < 4; ++rt)
#pragma unroll
            for (int r = 0; r < 4; ++r)
                lx[wr * 64 + rt * 16 + quad * 4 + r][col] = (bf16)gelu_f(acc[rt][ct][r] + bias);
    }
    __syncthreads();

    // ---- layer 3: K = 128 ----
#pragma unroll
    for (int i = 0; i < 4; ++i)
#pragma unroll
        for (int j = 0; j < 4; ++j) acc[i][j] = (f32x4){0.f, 0.f, 0.f, 0.f};
#pragma unroll
    for (int ks = 0; ks < 4; ++ks) {
        bf16x8 a[4], b[4];
#pragma unroll
        for (int rt = 0; rt < 4; ++rt)
            a[rt] = *(const bf16x8*)&lx[wr * 64 + rt * 16 + l16][ks * 32 + quad * 8];
#pragma unroll
        for (int ct = 0; ct < 4; ++ct)
            b[ct] = *(const bf16x8*)(W3b + (size_t)(wc * 64 + ct * 16 + l16) * HD + ks * 32 + quad * 8);
#pragma unroll
        for (int rt = 0; rt < 4; ++rt)
#pragma unroll
            for (int ct = 0; ct < 4; ++ct)
                acc[rt][ct] = __builtin_amdgcn_mfma_f32_16x16x32_bf16(a[rt], b[ct], acc[rt][ct], 0, 0, 0);
    }

    // epilogue 3: + b3, atomic scatter-add by src into segsum (= d_out)
    float b3c[4];
#pragma unroll
    for (int ct = 0; ct < 4; ++ct) b3c[ct] = b3[wc * 64 + ct * 16 + l16];
#pragma unroll
    for (int rt = 0; rt < 4; ++rt)
#pragma unroll
        for (int r = 0; r < 4; ++r) {
            int row = row0 + wr * 64 + rt * 16 + quad * 4 + r;
            float* basep = segsum + (size_t)src[row] * HD;
#pragma unroll
            for (int ct = 0; ct < 4; ++ct)
                atomicAdd(basep + wc * 64 + ct * 16 + l16, acc[rt][ct][r] + b3c[ct]);
        }
}

// ---- node: dh + residual + LN1 -> FFN (MFMA, FF in 64-col chunks) -> residual + LN2 ----
__global__ __launch_bounds__(256, 2) void node_ffn(
    const float* __restrict__ hV, float* __restrict__ out /* segsum in, h_V out */,
    const int* __restrict__ cnt,
    const bf16* __restrict__ Winb, const bf16* __restrict__ Woutb,
    const float* __restrict__ bin, const float* __restrict__ bout,
    const float* __restrict__ g1, const float* __restrict__ be1,
    const float* __restrict__ g2, const float* __restrict__ be2)
{
    __shared__ bf16 lx[128][136];     // LN1 output x (persists; also residual for LN2)
    __shared__ bf16 ly[128][72];      // gelu(x@Win.T) 64-col chunk
    __shared__ float ps[128][2], pq[128][2];
    const int tid  = threadIdx.x;
    const int wave = tid >> 6, lane = tid & 63;
    const int wr = wave >> 1, wc = wave & 1;
    const int quad = lane >> 4, l16 = lane & 15;
    const int base = blockIdx.x * 128;

    // phase 1: u = hV + segsum/max(cnt,1)/30 ; LN1 -> lx (bf16). one row per wave-iter.
    for (int r = 0; r < 32; ++r) {
        int rl = wave * 32 + r;
        int node = base + rl;
        float u0 = 0.f, u1 = 0.f;
        bool valid = node < NN;
        if (valid) {
            int c = cnt[node];
            float inv = 1.0f / (30.0f * (float)(c > 1 ? c : 1));
            const float2 h = *(const float2*)(hV  + (size_t)node * HD + 2 * lane);
            const float2 s = *(const float2*)(out + (size_t)node * HD + 2 * lane);
            u0 = h.x + s.x * inv;
            u1 = h.y + s.y * inv;
        }
        float sm = u0 + u1, sq = u0 * u0 + u1 * u1;
#pragma unroll
        for (int m = 1; m < 64; m <<= 1) {
            sm += __shfl_xor(sm, m, 64);
            sq += __shfl_xor(sq, m, 64);
        }
        float mean = sm * (1.0f / 128.0f);
        float var  = sq * (1.0f / 128.0f) - mean * mean;
        float rstd = rsqrtf(var + 1e-5f);
        int c0 = 2 * lane;
        float x0 = valid ? ((u0 - mean) * rstd * g1[c0]     + be1[c0])     : 0.f;
        float x1 = valid ? ((u1 - mean) * rstd * g1[c0 + 1] + be1[c0 + 1]) : 0.f;
        lx[rl][c0] = (bf16)x0; lx[rl][c0 + 1] = (bf16)x1;
    }
    __syncthreads();

    f32x4 oacc[4][4];
#pragma unroll
    for (int i = 0; i < 4; ++i)
#pragma unroll
        for (int j = 0; j < 4; ++j) oacc[i][j] = (f32x4){0.f, 0.f, 0.f, 0.f};

    for (int c = 0; c < 8; ++c) {   // FF=512 in 8 chunks of 64
        // GEMM1 chunk: y = gelu(x @ Win[c*64:+64].T + b_in)
        f32x4 a1[4][2];
#pragma unroll
        for (int i = 0; i < 4; ++i)
#pragma unroll
            for (int j = 0; j < 2; ++j) a1[i][j] = (f32x4){0.f, 0.f, 0.f, 0.f};
#pragma unroll
        for (int ks = 0; ks < 4; ++ks) {
            bf16x8 a[4], b[2];
#pragma unroll
            for (int rt = 0; rt < 4; ++rt)
                a[rt] = *(const bf16x8*)&lx[wr * 64 + rt * 16 + l16][ks * 32 + quad * 8];
#pragma unroll
            for (int ct = 0; ct < 2; ++ct) {
                int f = c * 64 + wc * 32 + ct * 16 + l16;
                b[ct] = *(const bf16x8*)(Winb + (size_t)f * HD + ks * 32 + quad * 8);
            }
#pragma unroll
            for (int rt = 0; rt < 4; ++rt)
#pragma unroll
                for (int ct = 0; ct < 2; ++ct)
                    a1[rt][ct] = __builtin_amdgcn_mfma_f32_16x16x32_bf16(a[rt], b[ct], a1[rt][ct], 0, 0, 0);
        }
        __syncthreads();   // prior chunk's GEMM2 reads of ly complete
#pragma unroll
        for (int ct = 0; ct < 2; ++ct) {
            int f  = c * 64 + wc * 32 + ct * 16 + l16;
            int fl = wc * 32 + ct * 16 + l16;
            float bias = bin[f];
#pragma unroll
            for (int rt = 0; rt < 4; ++rt)
#pragma unroll
                for (int r = 0; r < 4; ++r)
                    ly[wr * 64 + rt * 16 + quad * 4 + r][fl] = (bf16)gelu_f(a1[rt][ct][r] + bias);
        }
        __syncthreads();
        // GEMM2 partial: out += y @ Wout[:, c*64:+64].T
#pragma unroll
        for (int ks = 0; ks < 2; ++ks) {
            bf16x8 a[4], b[4];
#pragma unroll
            for (int rt = 0; rt < 4; ++rt)
                a[rt] = *(const bf16x8*)&ly[wr * 64 + rt * 16 + l16][ks * 32 + quad * 8];
#pragma unroll
            for (int ct = 0; ct < 4; ++ct) {
                int o = wc * 64 + ct * 16 + l16;
                b[ct] = *(const bf16x8*)(Woutb + (size_t)o * FFD + c * 64 + ks * 32 + quad * 8);
            }
#pragma unroll
            for (int rt = 0; rt < 4; ++rt)
#pragma unroll
                for (int ct = 0; ct < 4; ++ct)
                    oacc[rt][ct] = __builtin_amdgcn_mfma_f32_16x16x32_bf16(a[rt], b[ct], oacc[rt][ct], 0, 0, 0);
        }
    }

    // z = ffn + b_out + x (residual); LN2 row stats via quad butterfly + LDS combine
    float bo[4];
#pragma unroll
    for (int ct = 0; ct < 4; ++ct) bo[ct] = bout[wc * 64 + ct * 16 + l16];
#pragma unroll
    for (int rt = 0; rt < 4; ++rt)
#pragma unroll
        for (int r = 0; r < 4; ++r) {
            int rl = wr * 64 + rt * 16 + quad * 4 + r;
            float sm = 0.f, sq = 0.f;
#pragma unroll
            for (int ct = 0; ct < 4; ++ct) {
                int o = wc * 64 + ct * 16 + l16;
                float zz = oacc[rt][ct][r] + bo[ct] + (float)lx[rl][o];
                oacc[rt][ct][r] = zz;
                sm += zz; sq += zz * zz;
            }
#pragma unroll
            for (int m = 1; m < 16; m <<= 1) {   // reduce across the 16 lanes of this quad
                sm += __shfl_xor(sm, m, 64);
                sq += __shfl_xor(sq, m, 64);
            }
            if (l16 == 0) { ps[rl][wc] = sm; pq[rl][wc] = sq; }
        }
    __syncthreads();
#pragma unroll
    for (int rt = 0; rt < 4; ++rt)
#pragma unroll
        for (int r = 0; r < 4; ++r) {
            int rl = wr * 64 + rt * 16 + quad * 4 + r;
            int node = base + rl;
            float S = ps[rl][0] + ps[rl][1];
            float Q = pq[rl][0] + pq[rl][1];
            float mean = S * (1.0f / 128.0f);
            float var  = Q * (1.0f / 128.0f) - mean * mean;
            float rstd = rsqrtf(var + 1e-5f);
            if (node < NN) {
#pragma unroll
                for (int ct = 0; ct < 4; ++ct) {
                    int o = wc * 64 + ct * 16 + l16;
                    out[(size_t)node * HD + o] = (oacc[rt][ct][r] - mean) * rstd * g2[o] + be2[o];
                }
            }
        }
}

extern "C" void kernel_launch(void* const* d_in, const int* in_sizes, int n_in,
                              void* d_out, int out_size, void* d_ws, size_t ws_size,
                              hipStream_t stream) {
    const float* hV   = (const float*)d_in[0];
    const float* hE   = (const float*)d_in[1];
    const int*   src  = (const int*)d_in[2];
    // d_in[3] batch_id unused
    const int*   dst  = (const int*)d_in[4];
    const float* W1   = (const float*)d_in[5];
    const float* b1   = (const float*)d_in[6];
    const float* W2   = (const float*)d_in[7];
    const float* b2   = (const float*)d_in[8];
    const float* W3   = (const float*)d_in[9];
    const float* b3   = (const float*)d_in[10];
    const float* g1   = (const float*)d_in[11];
    const float* be1  = (const float*)d_in[12];
    const float* g2   = (const float*)d_in[13];
    const float* be2  = (const float*)d_in[14];
    const float* Win  = (const float*)d_in[15];
    const float* bin  = (const float*)d_in[16];
    const float* Wout = (const float*)d_in[17];
    const float* bout = (const float*)d_in[18];

    float* out = (float*)d_out;
    bf16*  wbf = (bf16*)d_ws;                       // 212992 bf16 = 425984 B
    int*   cnt = (int*)((char*)d_ws + 425984);      // 50000 ints

    hipMemsetAsync(d_out, 0, (size_t)NN * HD * sizeof(float), stream);  // seg_sum acc
    hipMemsetAsync(cnt, 0, NN * sizeof(int), stream);

    cvt_weights<<<832, 256, 0, stream>>>(W1, W2, W3, Win, Wout, wbf);
    hist_kernel<<<(NE + 255) / 256, 256, 0, stream>>>(src, cnt);
    edge_mlp<<<NE / 128, 256, 0, stream>>>(hV, hE, src, dst,
                                           wbf, wbf + 49152, wbf + 65536,
                                           b1, b2, b3, out);
    node_ffn<<<(NN + 127) / 128, 256, 0, stream>>>(hV, out, cnt,
                                                   wbf + 81920, wbf + 147456,
                                                   bin, bout, g1, be1, g2, be2);
}